// Round 1
// baseline (89.334 us; speedup 1.0000x reference)
//
#include <hip/hip_runtime.h>
#include <math.h>

// ElasticSparseAttention: B=1, H=16, KVH=4, S=2048, D=64, W=64, layer 12/24.
// f32 in/out. One wave per (h,s) output row; lane j owns window slot j for
// QK/softmax, then lanes switch roles to dimension d for the PV phase.

#define NH   16
#define NKVH 4
#define SEQ  2048
#define HD   64
#define WIN  64

// Index-math constants, folded in double exactly as the Python source does,
// then rounded to f32 exactly as JAX weak-typing does.
#define ALPHA_F ((float)(12.0 / 23.0))
#define PD0_F   ((float)(64.0 * (1.0 - 12.0 / 23.0)))
#define NEG_MIN (-3.4028234663852886e38f)   // finfo(f32).min

__global__ __launch_bounds__(256) void esa_kernel(
    const float* __restrict__ q,
    const float* __restrict__ k,
    const float* __restrict__ v,
    float* __restrict__ out)
{
    const int lane = threadIdx.x & 63;
    const int wid  = threadIdx.x >> 6;
    const int pair = blockIdx.x * 4 + wid;   // pair = h*SEQ + s
    const int h    = pair >> 11;
    const int s    = pair & (SEQ - 1);
    const int kvh  = h >> 2;                 // jnp.repeat(k, 4, axis=1) -> h//4

    __shared__ float qs[4][HD];
    qs[wid][lane] = q[(size_t)(h * SEQ + s) * HD + lane];
    __syncthreads();

    // ---- elastic index math (must match JAX f32 semantics bit-exactly) ----
    // No FMA contraction: use explicit _rn intrinsics. round == rint (half-even).
    const int   end     = (s > WIN - 1) ? s : (WIN - 1);
    const float ids_len = (float)(end + 1);
    const float pd      = __fadd_rn(PD0_F, __fmul_rn(ids_len, ALPHA_F));
    float start_f       = rintf(__fsub_rn(ids_len, pd));
    if (start_f < 0.0f) start_f = 0.0f;
    const int   start   = (int)start_f;
    const float window  = (float)(end + 1 - start);          // int arith, then cvt
    const float spacing = __fmul_rn(window, 0.015625f);      // /64 (pow2: exact)

    const int j    = lane;
    const int rel0 = (int)rintf(__fmul_rn((float)j, spacing));
    const int rel1 = (int)rintf(__fmul_rn((float)(j + 1), spacing));
    const int basej    = start + rel0;                        // over[:, :W]
    const int shiftedj = start + rel1 - 1;                    // over[:, 1:] - 1

    const float iw   = __fdiv_rn((float)h, 15.0f);
    const float omiw = __fsub_rn(1.0f, iw);
    const float idxf = __fadd_rn(__fmul_rn((float)basej, omiw),
                                 __fmul_rn((float)shiftedj, iw));
    int idx = (int)rintf(idxf);
    const bool valid = (idx <= s);
    if (!valid) idx = 0;

    // ---- QK: lane j dots q-row (LDS broadcast) with its gathered K row ----
    const float4* krow = (const float4*)(k + ((size_t)(kvh * SEQ + idx)) * HD);
    const float4* qrow = (const float4*)qs[wid];
    float sc = 0.0f;
    #pragma unroll
    for (int i = 0; i < HD / 4; ++i) {
        float4 kk = krow[i];
        float4 qq = qrow[i];
        sc += qq.x * kk.x + qq.y * kk.y + qq.z * kk.z + qq.w * kk.w;
    }
    sc *= 0.125f;                 // D^-0.5
    if (!valid) sc = NEG_MIN;

    // ---- wave softmax over the 64 window slots ----
    float m = sc;
    #pragma unroll
    for (int off = 32; off; off >>= 1) m = fmaxf(m, __shfl_xor(m, off));
    const float e = expf(sc - m);          // masked lanes -> exp(-huge) = 0
    float ssum = e;
    #pragma unroll
    for (int off = 32; off; off >>= 1) ssum += __shfl_xor(ssum, off);

    // ---- PV: lanes switch to dimension d; loop j with scalar broadcasts ----
    const float* vbase = v + (size_t)kvh * SEQ * HD + lane;
    float o = 0.0f;
    #pragma unroll
    for (int jj = 0; jj < WIN; ++jj) {
        const int   ij = __builtin_amdgcn_readlane(idx, jj);
        const float pj = __uint_as_float(
            __builtin_amdgcn_readlane(__float_as_uint(e), jj));
        o += pj * vbase[(size_t)ij * HD];
    }
    out[(size_t)(h * SEQ + s) * HD + lane] = o / ssum;
}

extern "C" void kernel_launch(void* const* d_in, const int* in_sizes, int n_in,
                              void* d_out, int out_size, void* d_ws, size_t ws_size,
                              hipStream_t stream) {
    const float* q = (const float*)d_in[0];
    const float* k = (const float*)d_in[1];
    const float* v = (const float*)d_in[2];
    float* out = (float*)d_out;
    const int nblocks = NH * SEQ / 4;   // 4 waves/block, one (h,s) per wave
    esa_kernel<<<nblocks, 256, 0, stream>>>(q, k, v, out);
}

// Round 2
// 46.874 us; speedup vs baseline: 1.9058x; 1.9058x over previous
//
#include <hip/hip_runtime.h>
#include <math.h>

// ElasticSparseAttention: B=1, H=16, KVH=4, S=2048, D=64, W=64, layer 12/24.
// One wave per (h,s). QK phase: lane (r,c) r=lane>>2, c=lane&3 handles window
// slot j = p*16+r over 4 phases; the 4 lanes of a quad each load one 16B chunk
// of the same 64B cache line -> fully-coalesced gather (4x fewer L1
// transactions than one-row-per-lane). PV phase: lane = dimension d, serial
// readlane broadcast of (idx, prob) -> 256B coalesced row loads.

#define NH   16
#define SEQ  2048
#define HD   64
#define WIN  64

// Index-math constants folded in double exactly as Python does, then f32.
#define ALPHA_F ((float)(12.0 / 23.0))
#define PD0_F   ((float)(64.0 * (1.0 - 12.0 / 23.0)))
#define NEG_MIN (-3.4028234663852886e38f)

__global__ __launch_bounds__(256) void esa_kernel(
    const float* __restrict__ q,
    const float* __restrict__ k,
    const float* __restrict__ v,
    float* __restrict__ out)
{
    const int lane = threadIdx.x & 63;
    const int wid  = threadIdx.x >> 6;
    const int pair = blockIdx.x * 4 + wid;   // pair = h*SEQ + s
    const int h    = pair >> 11;
    const int s    = pair & (SEQ - 1);
    const int kvh  = h >> 2;

    __shared__ float qs[4][HD];
    qs[wid][lane] = q[(size_t)(h * SEQ + s) * HD + lane];
    __syncthreads();

    // ---- wave-uniform elastic params (bit-exact f32, no FMA contraction) ----
    const int   end     = (s > WIN - 1) ? s : (WIN - 1);
    const float ids_len = (float)(end + 1);
    const float pd      = __fadd_rn(PD0_F, __fmul_rn(ids_len, ALPHA_F));
    float start_f       = rintf(__fsub_rn(ids_len, pd));
    if (start_f < 0.0f) start_f = 0.0f;
    const int   start   = (int)start_f;
    const float window  = (float)(end + 1 - start);
    const float spacing = __fmul_rn(window, 0.015625f);   // /64 exact
    const float iw      = __fdiv_rn((float)h, 15.0f);
    const float omiw    = __fsub_rn(1.0f, iw);

    const int r = lane >> 2;   // window-slot-within-phase 0..15
    const int c = lane & 3;    // 16B chunk within 64B line, 0..3

    // hoisted q fragments: chunks c, c+4, c+8, c+12 (same for all phases)
    float4 qq[4];
    #pragma unroll
    for (int i = 0; i < 4; ++i)
        qq[i] = ((const float4*)qs[wid])[4 * i + c];

    const float* kbase = k + (size_t)kvh * SEQ * HD;

    // ---- QK: 4 phases x 16 rows; quad-per-row fully-coalesced gather ----
    float sc[4];
    int   idxar[4];
    #pragma unroll
    for (int p = 0; p < 4; ++p) {
        const int j    = p * 16 + r;
        const int rel0 = (int)rintf(__fmul_rn((float)j, spacing));
        const int rel1 = (int)rintf(__fmul_rn((float)(j + 1), spacing));
        const int basej    = start + rel0;      // over[:, :W]
        const int shiftedj = start + rel1 - 1;  // over[:, 1:] - 1
        const float idxf = __fadd_rn(__fmul_rn((float)basej, omiw),
                                     __fmul_rn((float)shiftedj, iw));
        int idx = (int)rintf(idxf);
        const bool valid = (idx <= s);
        if (!valid) idx = 0;
        idxar[p] = idx;

        const float4* krow = (const float4*)(kbase + (size_t)idx * HD);
        float dot = 0.0f;
        #pragma unroll
        for (int i = 0; i < 4; ++i) {
            float4 kk = krow[4 * i + c];        // instr i: line i of 16 rows
            dot += qq[i].x * kk.x + qq[i].y * kk.y
                 + qq[i].z * kk.z + qq[i].w * kk.w;
        }
        dot += __shfl_xor(dot, 1);              // reduce across the quad
        dot += __shfl_xor(dot, 2);
        sc[p] = valid ? dot * 0.125f : NEG_MIN; // D^-0.5, mask
    }

    // ---- softmax over 64 slots (values replicated x4 across c) ----
    float m = fmaxf(fmaxf(sc[0], sc[1]), fmaxf(sc[2], sc[3]));
    #pragma unroll
    for (int off = 4; off <= 32; off <<= 1) m = fmaxf(m, __shfl_xor(m, off));
    float e[4];
    float ssum = 0.0f;
    #pragma unroll
    for (int p = 0; p < 4; ++p) { e[p] = expf(sc[p] - m); ssum += e[p]; }
    #pragma unroll
    for (int off = 4; off <= 32; off <<= 1) ssum += __shfl_xor(ssum, off);
    // offsets 4..32 sum across r only -> each slot counted once (c replicated)

    // ---- PV: lanes switch to dimension d; serial j with scalar broadcast ----
    // slot j lives in lanes where lane>>2 == (j&15), array element j>>4.
    const float* vbase = v + (size_t)kvh * SEQ * HD + lane;
    float o0 = 0.0f, o1 = 0.0f;
    #pragma unroll
    for (int jj = 0; jj < WIN; ++jj) {
        const int   ij = __builtin_amdgcn_readlane(idxar[jj >> 4], (jj & 15) * 4);
        const float pj = __uint_as_float(
            __builtin_amdgcn_readlane(__float_as_uint(e[jj >> 4]), (jj & 15) * 4));
        if (jj & 1) o1 += pj * vbase[(size_t)ij * HD];
        else        o0 += pj * vbase[(size_t)ij * HD];
    }
    out[(size_t)(h * SEQ + s) * HD + lane] = (o0 + o1) / ssum;
}

extern "C" void kernel_launch(void* const* d_in, const int* in_sizes, int n_in,
                              void* d_out, int out_size, void* d_ws, size_t ws_size,
                              hipStream_t stream) {
    const float* q = (const float*)d_in[0];
    const float* k = (const float*)d_in[1];
    const float* v = (const float*)d_in[2];
    float* out = (float*)d_out;
    const int nblocks = NH * SEQ / 4;   // 4 waves/block, one (h,s) per wave
    esa_kernel<<<nblocks, 256, 0, stream>>>(q, k, v, out);
}